// Round 1
// baseline (98.271 us; speedup 1.0000x reference)
//
#include <hip/hip_runtime.h>

#define HH 512
#define WW 512
#define HW (HH * WW)
#define RR 5
#define KS 11
#define EPS_F 1e-5f
#define NLOG2E 1.44269504088896340736f
#define TW 64                 // output tile width
#define TH 4                  // output tile height
#define BY 5                  // 320 threads = 5 waves
#define SW (TW + 2 * RR)      // 74: strip width (x-halo)
#define SH (TH + 2 * RR)      // 14: t-tile height (y-halo)
#define NSTRIP (SW * TH)      // 296 strip pixels <= 320 threads
#define NT (SH * SW)          // 1036 t-tile pixels

typedef float f2 __attribute__((ext_vector_type(2)));
__device__ __forceinline__ f2 fma2(f2 a, f2 b, f2 c) { return __builtin_elementwise_fma(a, b, c); }

// R10 = R9 with the t-power chain hoisted out of pass V.
// Theory: pass-V VALU issue binds (R5-calibrated). Per tap R9 spent ~6 serial
// muls (t2..t25 chain) + 3 pk_mul + 12 pk-acc + clamp/addr. The powers depend
// only on the tt pixel (reused by 4 ly-threads and 11 unroll steps), so phase 1
// now stores three f2 planes PA={1,t}, PB={t4,t9}, PC={t16,t25} (SoA f2 ->
// aligned ds_read_b64, pairs land directly in pk-operand register pairs).
// Tap body: 3 ds_read_b64 + 3 muls (img*u) + 12 pk_fma (w-class rides
// pk_fma(u,P) instead of pk_add). ~27 -> ~17 VALU/tap, no serial mul chain.
// OOB safety: masked t=0 pixels store PA={1,0},PB=PC=0; the literal 1 is only
// consumed at exponent 0 (i=0 row / j=0 col), which is always in-bounds, so
// every OOB tap still sees weight t^(>=1) = 0.
// Plus: y-interior fast path (124/128 block rows) drops per-tap ry clamps.
// LDS 32.6 -> 53.3 KB (3 blocks/CU by LDS; VGPRs likely capped us at ~15
// waves/CU already).
__global__ __launch_bounds__(320) void gauss_psf_kernel(const float* __restrict__ image,
                                                        const float* __restrict__ psf,
                                                        float* __restrict__ out) {
    __shared__ float4 cp[6 * NSTRIP];   // class planes (ch0,ch1,ch2,w), 28.4 KB
    __shared__ f2 pA[NT];               // {1, t}      8.3 KB
    __shared__ f2 pB[NT];               // {t^4, t^9}  8.3 KB
    __shared__ f2 pC[NT];               // {t^16,t^25} 8.3 KB

    const int tx  = threadIdx.x;            // 0..63
    const int ty  = threadIdx.y;            // 0..4
    const int tid = ty * 64 + tx;           // 0..319
    const int bx0 = blockIdx.x * TW;
    const int by0 = blockIdx.y * TH;
    const int b   = blockIdx.z;

    const float* pw   = psf + (size_t)b * HW;
    const float* img0 = image + (size_t)b * 3 * HW;

    // ---- Phase 1: masked-t powers tile (14 x 74 = 1036 records) ----
#pragma unroll
    for (int base = 0; base < NT; base += 320) {
        const int idx = base + tid;
        if (idx < NT) {
            const int row = idx / SW, col = idx - row * SW;
            const int gy = by0 - RR + row, gx = bx0 - RR + col;
            const bool in = ((unsigned)gy < (unsigned)HH) && ((unsigned)gx < (unsigned)WW);
            const int cy = gy < 0 ? 0 : (gy > HH - 1 ? HH - 1 : gy);
            const int cx = gx < 0 ? 0 : (gx > WW - 1 ? WW - 1 : gx);
            const float w = pw[cy * WW + cx];
            const float a = -NLOG2E * __builtin_amdgcn_rcpf(fmaf(2.0f * w, w, EPS_F));
            const float t = in ? __builtin_amdgcn_exp2f(a) : 0.0f;
            const float t2 = t * t, t4 = t2 * t2, t8 = t4 * t4;
            const float t9 = t8 * t, t16 = t8 * t8, t25 = t16 * t9;
            pA[idx] = (f2){1.0f, t};
            pB[idx] = (f2){t4, t9};
            pC[idx] = (f2){t16, t25};
        }
    }
    __syncthreads();

    // ---- Pass V: 296 strip pixels, one per thread ----
    if (tid < NSTRIP) {
        const int ly = tid / SW;            // 0..3
        const int lx = tid - ly * SW;       // 0..73
        const int gx = bx0 - RR + lx;
        const int gxc = gx < 0 ? 0 : (gx > WW - 1 ? WW - 1 : gx);
        const int gy = by0 + ly;
        const int sbase = ly * SW + lx;

        // Class-pair accumulators: [p] = classes (2p, 2p+1); channels 0,1,2 + w.
        f2 a0p[3], a1p[3], a2p[3], awp[3];
#pragma unroll
        for (int p = 0; p < 3; ++p) {
            a0p[p] = (f2)0.0f; a1p[p] = (f2)0.0f; a2p[p] = (f2)0.0f; awp[p] = (f2)0.0f;
        }

        // Tap body: r is constexpr after unroll -> u select folds to a register.
        auto tap = [&](int r, float i0, float i1, float i2) {
            const int si = sbase + r * SW;
            const f2 PA = pA[si];                              // {1, t}
            const f2 PB = pB[si];                              // {t4, t9}
            const f2 PC = pC[si];                              // {t16, t25}
            const int ii = (r - RR) * (r - RR);
            const float u = ii == 0 ? 1.0f : ii == 1 ? PA.y : ii == 4 ? PB.x
                          : ii == 9 ? PB.y : ii == 16 ? PC.x : PC.y;  // t^(i^2)
            const float j0 = i0 * u, j1 = i1 * u, j2 = i2 * u; // fold img*t^(i^2)
            const f2 j0v = {j0, j0}, j1v = {j1, j1}, j2v = {j2, j2}, uv = {u, u};
            a0p[0] = fma2(j0v, PA, a0p[0]);
            a0p[1] = fma2(j0v, PB, a0p[1]);
            a0p[2] = fma2(j0v, PC, a0p[2]);
            a1p[0] = fma2(j1v, PA, a1p[0]);
            a1p[1] = fma2(j1v, PB, a1p[1]);
            a1p[2] = fma2(j1v, PC, a1p[2]);
            a2p[0] = fma2(j2v, PA, a2p[0]);
            a2p[1] = fma2(j2v, PB, a2p[1]);
            a2p[2] = fma2(j2v, PC, a2p[2]);
            awp[0] = fma2(uv, PA, awp[0]);                     // w-class: pk_fma
            awp[1] = fma2(uv, PB, awp[1]);
            awp[2] = fma2(uv, PC, awp[2]);
        };

        if (by0 >= 2 * TH && by0 + TH + RR <= HH) {
            // y-interior (124/128 rows of blocks): no clamps, strength-reduced addrs
            const float* pb = img0 + (size_t)(gy - RR) * WW + gxc;
#pragma unroll
            for (int r = 0; r < KS; ++r)
                tap(r, pb[r * WW], pb[r * WW + HW], pb[r * WW + 2 * HW]);
        } else {
#pragma unroll
            for (int r = 0; r < KS; ++r) {
                int ry = gy + r - RR;
                ry = ry < 0 ? 0 : (ry > HH - 1 ? HH - 1 : ry);
                const int ni = ry * WW + gxc;
                tap(r, img0[ni], img0[ni + HW], img0[ni + 2 * HW]);
            }
        }

#pragma unroll
        for (int p = 0; p < 3; ++p) {                          // 6 ds_write_b128
            cp[(2 * p) * NSTRIP + tid]     = make_float4(a0p[p].x, a1p[p].x, a2p[p].x, awp[p].x);
            cp[(2 * p + 1) * NSTRIP + tid] = make_float4(a0p[p].y, a1p[p].y, a2p[p].y, awp[p].y);
        }
    }
    __syncthreads();

    // ---- Pass H: 256 output pixels (waves 0-3); wave 4 exits uniformly ----
    if (tid < TW * TH) {
        const int hx = tid & 63, hy = tid >> 6;
        const int hb = hy * SW + hx;        // strip index of (y, x-RR+j) at j=0
        f2 s01 = (f2)0.0f, s2w = (f2)0.0f;
#pragma unroll
        for (int j = 0; j < KS; ++j) {
            const int jj = (j - RR) * (j - RR);                // constexpr
            const int ai = jj == 0 ? 0 : jj == 1 ? 1 : jj == 4 ? 2
                         : jj == 9 ? 3 : jj == 16 ? 4 : 5;
            const float4 v = cp[ai * NSTRIP + hb + j];         // ds_read_b128
            s01 += (f2){v.x, v.y};                             // pk_add
            s2w += (f2){v.z, v.w};
        }

        const float sw = s2w.y;                                // >= 1 (center tap)
        float inv = __builtin_amdgcn_rcpf(sw);
        inv = inv * (2.0f - sw * inv);                         // Newton: ~1e-7 rel
        const int x = bx0 + hx, y = by0 + hy;
        const int oi = y * WW + x;
        float* outb = out + (size_t)b * 3 * HW;
        outb[oi]          = s01.x * inv;
        outb[HW + oi]     = s01.y * inv;
        outb[2 * HW + oi] = s2w.x * inv;
    }
}

extern "C" void kernel_launch(void* const* d_in, const int* in_sizes, int n_in,
                              void* d_out, int out_size, void* d_ws, size_t ws_size,
                              hipStream_t stream) {
    const float* image = (const float*)d_in[0];
    const float* psf   = (const float*)d_in[1];
    float* out = (float*)d_out;

    dim3 block(TW, BY, 1);                 // 320 threads = 5 waves
    dim3 grid(WW / TW, HH / TH, 4);        // 8 x 128 x 4 = 4096 blocks
    gauss_psf_kernel<<<grid, block, 0, stream>>>(image, psf, out);
}

// Round 2
// 84.541 us; speedup vs baseline: 1.1624x; 1.1624x over previous
//
#include <hip/hip_runtime.h>

#define HH 512
#define WW 512
#define HW (HH * WW)
#define RR 5
#define KS 11
#define EPS_F 1e-5f
#define NLOG2E 1.44269504088896340736f
#define TW 64                 // output tile width
#define TH 4                  // output tile height
#define BY 5                  // 320 threads = 5 waves
#define SW (TW + 2 * RR)      // 74: strip width (x-halo)
#define SH (TH + 2 * RR)      // 14: t-tile height (y-halo)
#define NSTRIP (SW * TH)      // 296 strip pixels <= 320 threads
#define NT (SH * SW)          // 1036 halo-tile pixels

typedef float f2 __attribute__((ext_vector_type(2)));
__device__ __forceinline__ f2 fma2(f2 a, f2 b, f2 c) { return __builtin_elementwise_fma(a, b, c); }

// R11: R9 accumulation structure (powers in registers — R10's LDS-hoist of
// powers REGRESSED 86.5->98.3, proving the kernel is latency/occupancy-bound,
// not VALU-issue-bound) + full strip staging in LDS.
// Phase 1 now stages float4(t, i0, i1, i2) per halo pixel: 4 global loads per
// pixel (psf + 3ch, shared clamped address), breadth-first -> latency hidden
// by pipelining instead of per-tap vmcnt waits. Pass V's tap body is ONE
// ds_read_b128 (single base, compile-time offset, no clamps, no addr math)
// + 6 power muls + 12 pk-fma. Global VMEM per thread: 33+4 -> ~16, all
// up-front; redundant 4x image loads (per-ly) eliminated.
// LDS overlay: strip (16.6 KB, NT float4) and cp (28.4 KB) share one 28.4 KB
// union — strip is dead after the tap loop, a barrier separates the last
// strip read from the first cp write (accumulators live in VGPRs across it).
// Occupancy: 28.4 KB < R9's 32.5 KB -> still 5 blocks/CU by LDS; VGPRs drop
// (no in-flight global loads in pass V).
__global__ __launch_bounds__(320) void gauss_psf_kernel(const float* __restrict__ image,
                                                        const float* __restrict__ psf,
                                                        float* __restrict__ out) {
    __shared__ float4 sm[6 * NSTRIP];   // 1776 float4 = 28.4 KB (union: strip | cp)

    const int tx  = threadIdx.x;            // 0..63
    const int ty  = threadIdx.y;            // 0..4
    const int tid = ty * 64 + tx;           // 0..319
    const int bx0 = blockIdx.x * TW;
    const int by0 = blockIdx.y * TH;
    const int b   = blockIdx.z;

    const float* pw   = psf + (size_t)b * HW;
    const float* img0 = image + (size_t)b * 3 * HW;

    // ---- Phase 1: stage (t, ch0, ch1, ch2) for the 14 x 74 halo tile ----
#pragma unroll
    for (int base = 0; base < NT; base += 320) {
        const int idx = base + tid;
        if (idx < NT) {
            const int row = idx / SW, col = idx - row * SW;
            const int gy = by0 - RR + row, gx = bx0 - RR + col;
            const bool in = ((unsigned)gy < (unsigned)HH) && ((unsigned)gx < (unsigned)WW);
            const int cy = gy < 0 ? 0 : (gy > HH - 1 ? HH - 1 : gy);
            const int cx = gx < 0 ? 0 : (gx > WW - 1 ? WW - 1 : gx);
            const int ni = cy * WW + cx;
            const float w  = pw[ni];
            const float i0 = img0[ni];
            const float i1 = img0[ni + HW];
            const float i2 = img0[ni + 2 * HW];
            const float a = -NLOG2E * __builtin_amdgcn_rcpf(fmaf(2.0f * w, w, EPS_F));
            const float t = in ? __builtin_amdgcn_exp2f(a) : 0.0f;
            sm[idx] = make_float4(t, i0, i1, i2);   // OOB: t=0 kills the tap; img value irrelevant
        }
    }
    __syncthreads();

    // ---- Pass V: 296 strip pixels, one per thread; LDS-only tap loop ----
    // Class-pair accumulators: [p] = classes (2p, 2p+1); channels 0,1,2 + w.
    // Function scope: live across the strip->cp overlay barrier in registers.
    f2 a0p[3], a1p[3], a2p[3], awp[3];
#pragma unroll
    for (int p = 0; p < 3; ++p) {
        a0p[p] = (f2)0.0f; a1p[p] = (f2)0.0f; a2p[p] = (f2)0.0f; awp[p] = (f2)0.0f;
    }

    if (tid < NSTRIP) {
        const int ly = tid / SW;            // 0..3
        const int lx = tid - ly * SW;       // 0..73
        const int sidx = ly * SW + lx;      // strip base; taps at +r*SW (imm offsets)

#pragma unroll
        for (int r = 0; r < KS; ++r) {
            const float4 v = sm[sidx + r * SW];                // 1 ds_read_b128, imm off
            const float t = v.x, i0 = v.y, i1 = v.z, i2 = v.w;

            // powers t^{1,4,9,16,25} (6 muls)
            const float t2 = t * t, t4 = t2 * t2, t8 = t4 * t4;
            const float t9 = t8 * t, t16 = t8 * t8, t25 = t16 * t9;

            const int ii = (r - RR) * (r - RR);                // constexpr after unroll
            const float u = ii == 0 ? 1.0f : ii == 1 ? t : ii == 4 ? t4
                          : ii == 9 ? t9 : ii == 16 ? t16 : t25;   // t^(i^2)

            const f2 u2  = {u, u};
            const f2 f01 = u2 * (f2){1.0f, t};                 // t^(i^2+{0,1})
            const f2 f23 = u2 * (f2){t4, t9};                  // t^(i^2+{4,9})
            const f2 f45 = u2 * (f2){t16, t25};                // t^(i^2+{16,25})

            const f2 i0v = {i0, i0}, i1v = {i1, i1}, i2v = {i2, i2};
            a0p[0] = fma2(i0v, f01, a0p[0]);
            a0p[1] = fma2(i0v, f23, a0p[1]);
            a0p[2] = fma2(i0v, f45, a0p[2]);
            a1p[0] = fma2(i1v, f01, a1p[0]);
            a1p[1] = fma2(i1v, f23, a1p[1]);
            a1p[2] = fma2(i1v, f45, a1p[2]);
            a2p[0] = fma2(i2v, f01, a2p[0]);
            a2p[1] = fma2(i2v, f23, a2p[1]);
            a2p[2] = fma2(i2v, f45, a2p[2]);
            awp[0] += f01;
            awp[1] += f23;
            awp[2] += f45;
        }
    }
    __syncthreads();                        // strip dead -> cp may reuse the union

    if (tid < NSTRIP) {
#pragma unroll
        for (int p = 0; p < 3; ++p) {                          // 6 ds_write_b128
            sm[(2 * p) * NSTRIP + tid]     = make_float4(a0p[p].x, a1p[p].x, a2p[p].x, awp[p].x);
            sm[(2 * p + 1) * NSTRIP + tid] = make_float4(a0p[p].y, a1p[p].y, a2p[p].y, awp[p].y);
        }
    }
    __syncthreads();

    // ---- Pass H: 256 output pixels (waves 0-3); wave 4 exits uniformly ----
    if (tid < TW * TH) {
        const int hx = tid & 63, hy = tid >> 6;
        const int hb = hy * SW + hx;        // strip index of (y, x-RR+j) at j=0
        f2 s01 = (f2)0.0f, s2w = (f2)0.0f;
#pragma unroll
        for (int j = 0; j < KS; ++j) {
            const int jj = (j - RR) * (j - RR);                // constexpr
            const int ai = jj == 0 ? 0 : jj == 1 ? 1 : jj == 4 ? 2
                         : jj == 9 ? 3 : jj == 16 ? 4 : 5;
            const float4 v = sm[ai * NSTRIP + hb + j];         // ds_read_b128
            s01 += (f2){v.x, v.y};                             // pk_add
            s2w += (f2){v.z, v.w};
        }

        const float sw = s2w.y;                                // >= 1 (center tap)
        float inv = __builtin_amdgcn_rcpf(sw);
        inv = inv * (2.0f - sw * inv);                         // Newton: ~1e-7 rel
        const int x = bx0 + hx, y = by0 + hy;
        const int oi = y * WW + x;
        float* outb = out + (size_t)b * 3 * HW;
        outb[oi]          = s01.x * inv;
        outb[HW + oi]     = s01.y * inv;
        outb[2 * HW + oi] = s2w.x * inv;
    }
}

extern "C" void kernel_launch(void* const* d_in, const int* in_sizes, int n_in,
                              void* d_out, int out_size, void* d_ws, size_t ws_size,
                              hipStream_t stream) {
    const float* image = (const float*)d_in[0];
    const float* psf   = (const float*)d_in[1];
    float* out = (float*)d_out;

    dim3 block(TW, BY, 1);                 // 320 threads = 5 waves
    dim3 grid(WW / TW, HH / TH, 4);        // 8 x 128 x 4 = 4096 blocks
    gauss_psf_kernel<<<grid, block, 0, stream>>>(image, psf, out);
}